// Round 17
// baseline (1004.820 us; speedup 1.0000x reference)
//
#include <hip/hip_runtime.h>
#include <hip/hip_bf16.h>

// POS tagger forward: char-conv word features + word emb -> 2-layer LSTM (H=250) -> dense(45)
// B=512, S=64.
//
// ROUND 17: in-register pointwise + single barrier/step. Wave w computes ALL 4 gates for
// cols [w*16,w*16+16); MFMA C/D layout puts all 4 gate pre-acts for (batch j, col) in one
// lane -> pointwise on q==0 lanes with c_reg[4], g_s/c_s deleted. h_s parity-double-buffered
// -> ONE barrier per step. NRES=7 whh fragments resident in LDS (round-16 win kept).
// 128 blocks x 4 batches, 1 block/CU (144.6 KB LDS), no manual load pipelining.

#define Bb 512
#define Ss 64
#define Ww 12
#define Tt 45
#define CEe 10
#define Ff 32
#define Hh 250
#define Mtok (Bb*Ss)      // 32768
#define KP0 288           // 282 padded to 9*32
#define KP1 256           // 250 padded to 8*32
#define NGP 1024          // gates padded: 4 sections of 256
#define XPAD 1036         // xg LDS row stride (bank-spread)
#define NB 4              // batches per LSTM block
#define NBLK (Bb/NB)      // 128 LSTM blocks
#define NRES 7            // resident whh fragments per wave (of 32)

typedef float f32x4 __attribute__((ext_vector_type(4)));
typedef __bf16 bf16x8 __attribute__((ext_vector_type(8)));

__device__ inline unsigned short f2bu(float f) {
  return __builtin_bit_cast(unsigned short, __float2bfloat16(f));
}
__device__ inline float bu2f(unsigned short u) {
  return __bfloat162float(__builtin_bit_cast(__hip_bfloat16, u));
}
__device__ inline float sigm(float x) { return 1.f / (1.f + __expf(-x)); }
__device__ inline float tanh_f(float x) { float e = __expf(2.f*x); return 1.f - 2.f/(e+1.f); }

// dtype-adaptive loads: f32flag ? float data : bf16(u16) data
__device__ inline float ldf(const void* p, size_t i, int f32) {
  return f32 ? ((const float*)p)[i] : bu2f(((const unsigned short*)p)[i]);
}
__device__ inline unsigned short ldb(const void* p, size_t i, int f32) {
  return f32 ? f2bu(((const float*)p)[i]) : ((const unsigned short*)p)[i];
}

// ---------------- dtype detection ----------------
__global__ void detect_dtype(const unsigned short* __restrict__ wemb_u16, int* __restrict__ flag) {
  if (threadIdx.x == 0) {
    int cnt = 0;
    for (int i = 0; i < 64; ++i) {
      unsigned short v = wemb_u16[2*i];
      int e = (v >> 7) & 0xFF;
      cnt += (e >= 127) ? 1 : 0;
    }
    *flag = (cnt > 0) ? 1 : 0;
  }
}

// ---------------- weight prep ----------------
// wih*: rows 0..999 orig order (+pad to 1024x{288,256}).
// whh*: packed for coalesced wave loads: idx = ((((w8*4+g)*2+t)*8+kt)*64+lane)*8+e
//       <- orig whh[g*250 + (w8*32+t*16+(lane&15))][kt*32 + (lane>>4)*8 + e]  (0-pad invalid)
#define R_WIH0 (1024*288)
#define R_W256 (1024*256)
#define R_WD   (128*256)
#define PREP_TOTAL (R_WIH0 + 3*R_W256 + R_WD + 1024 + 1024 + 128)

__global__ void prep_weights(const void* __restrict__ wih0, const void* __restrict__ wih1,
                             const void* __restrict__ whh0, const void* __restrict__ whh1,
                             const void* __restrict__ dw,
                             const void* __restrict__ bih0, const void* __restrict__ bhh0,
                             const void* __restrict__ bih1, const void* __restrict__ bhh1,
                             const void* __restrict__ db,
                             unsigned short* __restrict__ wih0p, unsigned short* __restrict__ wih1p,
                             unsigned short* __restrict__ whh0p, unsigned short* __restrict__ whh1p,
                             unsigned short* __restrict__ wdp,
                             float* __restrict__ bias0, float* __restrict__ bias1, float* __restrict__ biasd,
                             const int* __restrict__ flagp)
{
  const int f = *flagp;
  int idx = blockIdx.x * 256 + threadIdx.x;
  if (idx < R_WIH0) {
    int n = idx / 288, k = idx % 288;
    wih0p[idx] = (n < 1000 && k < 282) ? ldb(wih0, (size_t)n*282 + k, f) : 0;
    return;
  }
  idx -= R_WIH0;
  if (idx < R_W256) { int n = idx/256, k = idx%256; wih1p[idx] = (n<1000 && k<250) ? ldb(wih1, (size_t)n*250+k, f) : 0; return; }
  idx -= R_W256;
  if (idx < R_W256) {  // whh0 coalesced-pack [w8][g][t][kt][lane][8]
    int e = idx & 7, lane = (idx>>3)&63, kt = (idx>>9)&7, t = (idx>>12)&1, g = (idx>>13)&3, w = idx>>15;
    int r = lane & 15, q = lane >> 4;
    int jj = w*32 + t*16 + r, k = kt*32 + q*8 + e;
    whh0p[idx] = (jj<250 && k<250) ? ldb(whh0, (size_t)(g*250+jj)*250 + k, f) : 0;
    return;
  }
  idx -= R_W256;
  if (idx < R_W256) {  // whh1 coalesced-pack
    int e = idx & 7, lane = (idx>>3)&63, kt = (idx>>9)&7, t = (idx>>12)&1, g = (idx>>13)&3, w = idx>>15;
    int r = lane & 15, q = lane >> 4;
    int jj = w*32 + t*16 + r, k = kt*32 + q*8 + e;
    whh1p[idx] = (jj<250 && k<250) ? ldb(whh1, (size_t)(g*250+jj)*250 + k, f) : 0;
    return;
  }
  idx -= R_W256;
  if (idx < R_WD)   { int n = idx/256, k = idx%256; wdp[idx] = (n<45 && k<250) ? ldb(dw, (size_t)n*250+k, f) : 0; return; }
  idx -= R_WD;
  if (idx < 1024) { bias0[idx] = (idx<1000) ? ldf(bih0, idx, f) + ldf(bhh0, idx, f) : 0.f; return; }
  idx -= 1024;
  if (idx < 1024) { bias1[idx] = (idx<1000) ? ldf(bih1, idx, f) + ldf(bhh1, idx, f) : 0.f; return; }
  idx -= 1024;
  if (idx < 128)  { biasd[idx] = (idx<45) ? ldf(db, idx, f) : 0.f; }
}

// ---------------- char conv + max + word-emb concat -> emb [32768][288] bf16 ----------------
__global__ void embed_conv(const int* __restrict__ ci, const int* __restrict__ wi,
                           const void* __restrict__ cemb,
                           const void* __restrict__ wemb,
                           const void* __restrict__ cw,
                           const void* __restrict__ cb,
                           unsigned short* __restrict__ emb,
                           const int* __restrict__ flagp)
{
  __shared__ float s_cw[960];
  __shared__ float s_cb[32];
  __shared__ float s_ce[1000];
  __shared__ int   s_ind[4][12];
  __shared__ float s_ct[4][120];
  const int f = *flagp;
  const int tid = threadIdx.x;
  for (int i = tid; i < 960; i += 256) s_cw[i] = ldf(cw, i, f);
  if (tid < 32) s_cb[tid] = ldf(cb, tid, f);
  for (int i = tid; i < 1000; i += 256) s_ce[i] = ldf(cemb, i, f);
  __syncthreads();
  const int wv = tid >> 6, lane = tid & 63;
  const int tok = blockIdx.x * 4 + wv;
  if (lane < 12) s_ind[wv][lane] = ci[tok*12 + lane];
  __syncthreads();
#pragma unroll
  for (int p = 0; p < 2; ++p) {
    int pos = p*64 + lane;
    if (pos < 120) {
      int w = pos / 10, ce = pos % 10;
      s_ct[wv][pos] = s_ce[s_ind[wv][w]*10 + ce];
    }
  }
  __syncthreads();
  if (lane < 32) {
    const int ff = lane;
    float mx = -1e30f;
    for (int p = 0; p < Ww; ++p) {
      float acc = s_cb[ff];
#pragma unroll
      for (int k = 0; k < 3; ++k) {
        int wp = p + k - 1;
        if (wp >= 0 && wp < Ww) {
#pragma unroll
          for (int ce = 0; ce < CEe; ++ce)
            acc += s_ct[wv][wp*10 + ce] * s_cw[ff*30 + ce*3 + k];
        }
      }
      mx = fmaxf(mx, acc);
    }
    emb[(size_t)tok*KP0 + ff] = f2bu(mx);
  }
  const int widx = wi[tok];
  for (int j = lane; j < 250; j += 64)
    emb[(size_t)tok*KP0 + Ff + j] = ldb(wemb, (size_t)widx*250 + j, f);
  if (lane >= 58) emb[(size_t)tok*KP0 + 282 + (lane - 58)] = 0;
}

// ---------------- bf16 MFMA GEMM: C[r][n] = sum_k A[r][k]*W[n][k] + bias[n] ----------------
template<int KC>
__global__ __launch_bounds__(256, 2) void gemm_bf16(
    const unsigned short* __restrict__ A, int lda,
    const unsigned short* __restrict__ Bw,
    const float* __restrict__ bias,
    void* __restrict__ Cout, int ldo, int nvalid,
    const int* __restrict__ flagp, int useflag, int gate_pad)
{
  __shared__ alignas(16) unsigned short lsA[128*32];
  __shared__ alignas(16) unsigned short lsB[128*32];
  const int tid = threadIdx.x;
  const int lane = tid & 63;
  const int w = tid >> 6;
  const int wr = w >> 1, wc = w & 1;
  const int mt = blockIdx.x, nt = blockIdx.y;

  f32x4 acc[4][4];
#pragma unroll
  for (int m = 0; m < 4; ++m)
#pragma unroll
    for (int n = 0; n < 4; ++n) acc[m][n] = (f32x4){0.f,0.f,0.f,0.f};

  for (int kt = 0; kt < KC; ++kt) {
    __syncthreads();
#pragma unroll
    for (int p = 0; p < 2; ++p) {
      int flat = p*256 + tid;
      int row = flat >> 2, c = flat & 3;
      *(bf16x8*)&lsA[flat*8] = *(const bf16x8*)(A  + (size_t)(mt*128 + row)*lda     + kt*32 + c*8);
      *(bf16x8*)&lsB[flat*8] = *(const bf16x8*)(Bw + (size_t)(nt*128 + row)*(KC*32) + kt*32 + c*8);
    }
    __syncthreads();
    bf16x8 a[4], b[4];
#pragma unroll
    for (int m = 0; m < 4; ++m) {
      int row = wr*64 + m*16 + (lane & 15);
      a[m] = *(const bf16x8*)&lsA[row*32 + (lane >> 4)*8];
    }
#pragma unroll
    for (int n = 0; n < 4; ++n) {
      int row = wc*64 + n*16 + (lane & 15);
      b[n] = *(const bf16x8*)&lsB[row*32 + (lane >> 4)*8];
    }
#pragma unroll
    for (int m = 0; m < 4; ++m)
#pragma unroll
      for (int n = 0; n < 4; ++n)
        acc[m][n] = __builtin_amdgcn_mfma_f32_16x16x32_bf16(a[m], b[n], acc[m][n], 0, 0, 0);
  }

  const bool of32 = useflag && (*flagp != 0);
  const int rbase = mt*128 + wr*64;
  const int cbase = nt*128 + wc*64;
#pragma unroll
  for (int m = 0; m < 4; ++m)
#pragma unroll
    for (int n = 0; n < 4; ++n) {
      int col = cbase + n*16 + (lane & 15);
      if (col < nvalid) {
        float bv = bias[col];
        int colw = col;
        if (gate_pad) {
          int g = (col>=250) + (col>=500) + (col>=750);
          colw = col + 6*g;
        }
#pragma unroll
        for (int j = 0; j < 4; ++j) {
          int row = rbase + m*16 + (lane >> 4)*4 + j;
          float val = acc[m][n][j] + bv;
          if (of32) ((float*)Cout)[(size_t)row*ldo + colw] = val;
          else      ((unsigned short*)Cout)[(size_t)row*ldo + colw] = f2bu(val);
        }
      }
    }
}

// ---------------- COMPACT 16-wave LSTM: in-register pointwise, single barrier/step --------
// xg: [32768][1024] bf16, cols gate-padded. whh: coalesced-packed (see prep).
// hout: [32768][256] bf16 (cols 250..255 zeroed). Wave w owns cols [w*16,w*16+16) for all
// 4 gates; lane (r,q) acc[g][j] = gate g, batch q*4+j, col w*16+r. q==0 lanes do pointwise
// in-register (c_reg[4]). h_s parity-dbuf: read [s&1], write [s&1^1] -> one barrier/step.
// NRES=7 fragments resident in LDS; remaining 25 streamed (per-CU port-bound, ~3us/step).
__global__ __launch_bounds__(1024) void lstm_c(
    const unsigned short* __restrict__ xg,
    const unsigned short* __restrict__ whh,
    unsigned short* __restrict__ hout)
{
  __shared__ alignas(16) unsigned short whl[16*NRES*64*8];  // 112 KB resident whh
  __shared__ alignas(16) unsigned short h_s[2][16*256];     // parity dbuf, swizzled chunk^(b&7)
  __shared__ alignas(16) unsigned short xg_l[2][NB*XPAD];   // dbuf
  const int tid = threadIdx.x;
  const int lane = tid & 63;
  const int w = tid >> 6;                                   // 0..15
  const int r = lane & 15, q = lane >> 4;
  const int bb0 = blockIdx.x * NB;
  const unsigned short* wbase = whh + (size_t)(w >> 1)*32768 + (size_t)(w & 1)*4096 + lane*8;
  const int col = w*16 + r;                                 // this lane's within-gate col

  // one-time: resident fragments (g=0, kt=0..6) -> LDS, lane-contiguous layout
#pragma unroll
  for (int f = 0; f < NRES; ++f)
    *(bf16x8*)&whl[((w*NRES + f)*64 + lane)*8] = *(const bf16x8*)(wbase + f*512);

  for (int i = tid; i < 2*16*256; i += 1024) ((unsigned short*)h_s)[i] = 0;
  float c_reg[4];
#pragma unroll
  for (int j = 0; j < 4; ++j) c_reg[j] = 0.f;
  if (tid < NB*128) {
    int row = tid >> 7, ch = tid & 127;
    *(bf16x8*)&xg_l[0][row*XPAD + ch*8] =
        *(const bf16x8*)(xg + (size_t)(bb0 + row)*1024 + ch*8);
  }
  __syncthreads();

  int cur = 0;
#pragma unroll 1
  for (int s = 0; s < Ss; ++s) {
    const int par = s & 1;
    // prefetch next step's xg (staged to LDS after pointwise)
    const int sp = (s + 1 < Ss) ? s + 1 : s;
    bf16x8 pf;
    if (tid < NB*128) {
      int row = tid >> 7, ch = tid & 127;
      pf = *(const bf16x8*)(xg + (size_t)(sp*512 + bb0 + row)*1024 + ch*8);
    }
    // A fragments (h_prev from parity buffer; rows >= NB are zeros)
    bf16x8 av[8];
#pragma unroll
    for (int kt = 0; kt < 8; ++kt) {
      int ch = (kt*4 + q) ^ (r & 7);
      av[kt] = *(const bf16x8*)&h_s[par][r*256 + ch*8];
    }
    // 4 gate tiles, fully unrolled (static acc indexing); g=0: NRES LDS + 1 global
    f32x4 acc[4];
#pragma unroll
    for (int g = 0; g < 4; ++g) acc[g] = (f32x4){0.f,0.f,0.f,0.f};
#pragma unroll
    for (int kt = 0; kt < NRES; ++kt) {
      bf16x8 bv = *(const bf16x8*)&whl[((w*NRES + kt)*64 + lane)*8];
      acc[0] = __builtin_amdgcn_mfma_f32_16x16x32_bf16(av[kt], bv, acc[0], 0, 0, 0);
    }
    {
      bf16x8 bv = *(const bf16x8*)(wbase + 7*512);
      acc[0] = __builtin_amdgcn_mfma_f32_16x16x32_bf16(av[7], bv, acc[0], 0, 0, 0);
    }
#pragma unroll
    for (int g = 1; g < 4; ++g) {
      const unsigned short* bp = wbase + g*8192;
#pragma unroll
      for (int kt = 0; kt < 8; ++kt) {
        bf16x8 bv = *(const bf16x8*)(bp + kt*32*16);   // kt*512
        acc[g] = __builtin_amdgcn_mfma_f32_16x16x32_bf16(av[kt], bv, acc[g], 0, 0, 0);
      }
    }
    // in-register pointwise on q==0 lanes (batches j=0..3 of this block)
    if (q == 0) {
      const unsigned short* xc = &xg_l[cur][0];
      const bool valid = col < Hh;
#pragma unroll
      for (int j = 0; j < 4; ++j) {
        float gi = acc[0][j] + bu2f(xc[j*XPAD + col]);
        float gf = acc[1][j] + bu2f(xc[j*XPAD + 256 + col]);
        float gg = acc[2][j] + bu2f(xc[j*XPAD + 512 + col]);
        float go = acc[3][j] + bu2f(xc[j*XPAD + 768 + col]);
        float c = sigm(gf)*c_reg[j] + sigm(gi)*tanh_f(gg);
        float h = sigm(go)*tanh_f(c);
        if (!valid) { c = 0.f; h = 0.f; }
        c_reg[j] = c;
        unsigned short hb = f2bu(h);
        h_s[par ^ 1][j*256 + (((col >> 3) ^ (j & 7)) << 3) + (col & 7)] = hb;
        hout[(size_t)(s*512 + bb0 + j)*256 + col] = hb;
      }
    }
    // stage prefetched xg into the other buffer
    if (tid < NB*128) {
      int row = tid >> 7, ch = tid & 127;
      *(bf16x8*)&xg_l[cur ^ 1][row*XPAD + ch*8] = pf;
    }
    __syncthreads();   // ONE barrier: h_s[par^1], xg_l[cur^1] ready; all reads of par done
    cur ^= 1;
  }
}

// ---------------- launcher ----------------
extern "C" void kernel_launch(void* const* d_in, const int* in_sizes, int n_in,
                              void* d_out, int out_size, void* d_ws, size_t ws_size,
                              hipStream_t stream) {
  (void)in_sizes; (void)n_in; (void)out_size;
  const int* ci = (const int*)d_in[0];
  const int* wi = (const int*)d_in[1];
  const void* cemb = d_in[2];
  const void* wemb = d_in[3];
  const void* cw   = d_in[4];
  const void* cb   = d_in[5];
  const void* wih0 = d_in[6];
  const void* whh0 = d_in[7];
  const void* bih0 = d_in[8];
  const void* bhh0 = d_in[9];
  const void* wih1 = d_in[10];
  const void* whh1 = d_in[11];
  const void* bih1 = d_in[12];
  const void* bhh1 = d_in[13];
  const void* dw   = d_in[14];
  const void* db   = d_in[15];

  // ws layout (bytes), weights first; total = 105,000,960
  constexpr size_t OFF_WIH0 = 0;
  constexpr size_t OFF_WIH1 = OFF_WIH0 + 589824;
  constexpr size_t OFF_WHH0 = OFF_WIH1 + 524288;
  constexpr size_t OFF_WHH1 = OFF_WHH0 + 524288;
  constexpr size_t OFF_WD   = OFF_WHH1 + 524288;
  constexpr size_t OFF_B0   = OFF_WD   + 65536;
  constexpr size_t OFF_B1   = OFF_B0   + 4096;
  constexpr size_t OFF_BD   = OFF_B1   + 4096;
  constexpr size_t OFF_FLAG = OFF_BD   + 2048;
  constexpr size_t OFF_H1   = OFF_BD   + 4096;
  constexpr size_t OFF_EMB  = OFF_H1   + 16777216;
  constexpr size_t OFF_XG   = OFF_EMB  + 18874368;
  constexpr size_t WS_NEED  = OFF_XG   + 67108864;
  if (ws_size < WS_NEED) return;

  char* ws = (char*)d_ws;
  unsigned short* WIH0 = (unsigned short*)(ws + OFF_WIH0);
  unsigned short* WIH1 = (unsigned short*)(ws + OFF_WIH1);
  unsigned short* WHH0 = (unsigned short*)(ws + OFF_WHH0);
  unsigned short* WHH1 = (unsigned short*)(ws + OFF_WHH1);
  unsigned short* WD   = (unsigned short*)(ws + OFF_WD);
  float* B0 = (float*)(ws + OFF_B0);
  float* B1 = (float*)(ws + OFF_B1);
  float* BD = (float*)(ws + OFF_BD);
  int* FLAG = (int*)(ws + OFF_FLAG);
  unsigned short* H1   = (unsigned short*)(ws + OFF_H1);
  unsigned short* EMB  = (unsigned short*)(ws + OFF_EMB);
  unsigned short* H2   = (unsigned short*)(ws + OFF_EMB);  // alias: EMB dead after xg0 gemm
  unsigned short* XG   = (unsigned short*)(ws + OFF_XG);

  detect_dtype<<<1, 64, 0, stream>>>((const unsigned short*)wemb, FLAG);
  prep_weights<<<(PREP_TOTAL + 255)/256, 256, 0, stream>>>(
      wih0, wih1, whh0, whh1, dw, bih0, bhh0, bih1, bhh1, db,
      WIH0, WIH1, WHH0, WHH1, WD, B0, B1, BD, FLAG);
  embed_conv<<<Mtok/4, 256, 0, stream>>>(ci, wi, cemb, wemb, cw, cb, EMB, FLAG);
  gemm_bf16<9><<<dim3(Mtok/128, NGP/128), 256, 0, stream>>>(EMB, KP0, WIH0, B0, XG, NGP, NGP, FLAG, 0, 1);
  lstm_c<<<NBLK, 1024, 0, stream>>>(XG, WHH0, H1);
  gemm_bf16<8><<<dim3(Mtok/128, NGP/128), 256, 0, stream>>>(H1, KP1, WIH1, B1, XG, NGP, NGP, FLAG, 0, 1);
  lstm_c<<<NBLK, 1024, 0, stream>>>(XG, WHH1, H2);
  gemm_bf16<8><<<dim3(Mtok/128, 1), 256, 0, stream>>>(H2, KP1, WD, BD, d_out, Tt, Tt, FLAG, 1, 0);
}

// Round 18
// 832.071 us; speedup vs baseline: 1.2076x; 1.2076x over previous
//
#include <hip/hip_runtime.h>
#include <hip/hip_bf16.h>

// POS tagger forward: char-conv word features + word emb -> 2-layer LSTM (H=250) -> dense(45)
// B=512, S=64.
//
// ROUND 18: in-register pointwise FIXED. Round 17's two regressions: (a) hout writes from
// 16 lanes -> 32B partial-line traffic (WRITE 16->39MB); (b) pointwise TRANS in 16/64 lanes
// (4x per-wave TRANS). Fix: replicate batches in h_s rows (row -> batch row>>2) so lane
// (r,q) reads acc[g][0] (STATIC index) for (batch q, col w*16+r) -> pointwise across all
// 64 lanes, scalar c_reg; h written to LDS only; hout stored by a coalesced h_s->global
// copy phase overlapped into the next step (parity dbuf, no extra barrier).
// NRES=7 whh LDS residency + 128 blocks x 4 batches kept (round-16 wins).

#define Bb 512
#define Ss 64
#define Ww 12
#define Tt 45
#define CEe 10
#define Ff 32
#define Hh 250
#define Mtok (Bb*Ss)      // 32768
#define KP0 288           // 282 padded to 9*32
#define KP1 256           // 250 padded to 8*32
#define NGP 1024          // gates padded: 4 sections of 256
#define XPAD 1036         // xg LDS row stride (bank-spread)
#define NB 4              // batches per LSTM block
#define NBLK (Bb/NB)      // 128 LSTM blocks
#define NRES 7            // resident whh fragments per wave (of 32)

typedef float f32x4 __attribute__((ext_vector_type(4)));
typedef __bf16 bf16x8 __attribute__((ext_vector_type(8)));

__device__ inline unsigned short f2bu(float f) {
  return __builtin_bit_cast(unsigned short, __float2bfloat16(f));
}
__device__ inline float bu2f(unsigned short u) {
  return __bfloat162float(__builtin_bit_cast(__hip_bfloat16, u));
}
__device__ inline float sigm(float x) { return 1.f / (1.f + __expf(-x)); }
__device__ inline float tanh_f(float x) { float e = __expf(2.f*x); return 1.f - 2.f/(e+1.f); }

// dtype-adaptive loads: f32flag ? float data : bf16(u16) data
__device__ inline float ldf(const void* p, size_t i, int f32) {
  return f32 ? ((const float*)p)[i] : bu2f(((const unsigned short*)p)[i]);
}
__device__ inline unsigned short ldb(const void* p, size_t i, int f32) {
  return f32 ? f2bu(((const float*)p)[i]) : ((const unsigned short*)p)[i];
}

// ---------------- dtype detection ----------------
__global__ void detect_dtype(const unsigned short* __restrict__ wemb_u16, int* __restrict__ flag) {
  if (threadIdx.x == 0) {
    int cnt = 0;
    for (int i = 0; i < 64; ++i) {
      unsigned short v = wemb_u16[2*i];
      int e = (v >> 7) & 0xFF;
      cnt += (e >= 127) ? 1 : 0;
    }
    *flag = (cnt > 0) ? 1 : 0;
  }
}

// ---------------- weight prep ----------------
// wih*: rows 0..999 orig order (+pad to 1024x{288,256}).
// whh*: packed for coalesced wave loads: idx = ((((w8*4+g)*2+t)*8+kt)*64+lane)*8+e
//       <- orig whh[g*250 + (w8*32+t*16+(lane&15))][kt*32 + (lane>>4)*8 + e]  (0-pad invalid)
#define R_WIH0 (1024*288)
#define R_W256 (1024*256)
#define R_WD   (128*256)
#define PREP_TOTAL (R_WIH0 + 3*R_W256 + R_WD + 1024 + 1024 + 128)

__global__ void prep_weights(const void* __restrict__ wih0, const void* __restrict__ wih1,
                             const void* __restrict__ whh0, const void* __restrict__ whh1,
                             const void* __restrict__ dw,
                             const void* __restrict__ bih0, const void* __restrict__ bhh0,
                             const void* __restrict__ bih1, const void* __restrict__ bhh1,
                             const void* __restrict__ db,
                             unsigned short* __restrict__ wih0p, unsigned short* __restrict__ wih1p,
                             unsigned short* __restrict__ whh0p, unsigned short* __restrict__ whh1p,
                             unsigned short* __restrict__ wdp,
                             float* __restrict__ bias0, float* __restrict__ bias1, float* __restrict__ biasd,
                             const int* __restrict__ flagp)
{
  const int f = *flagp;
  int idx = blockIdx.x * 256 + threadIdx.x;
  if (idx < R_WIH0) {
    int n = idx / 288, k = idx % 288;
    wih0p[idx] = (n < 1000 && k < 282) ? ldb(wih0, (size_t)n*282 + k, f) : 0;
    return;
  }
  idx -= R_WIH0;
  if (idx < R_W256) { int n = idx/256, k = idx%256; wih1p[idx] = (n<1000 && k<250) ? ldb(wih1, (size_t)n*250+k, f) : 0; return; }
  idx -= R_W256;
  if (idx < R_W256) {  // whh0 coalesced-pack [w8][g][t][kt][lane][8]
    int e = idx & 7, lane = (idx>>3)&63, kt = (idx>>9)&7, t = (idx>>12)&1, g = (idx>>13)&3, w = idx>>15;
    int r = lane & 15, q = lane >> 4;
    int jj = w*32 + t*16 + r, k = kt*32 + q*8 + e;
    whh0p[idx] = (jj<250 && k<250) ? ldb(whh0, (size_t)(g*250+jj)*250 + k, f) : 0;
    return;
  }
  idx -= R_W256;
  if (idx < R_W256) {  // whh1 coalesced-pack
    int e = idx & 7, lane = (idx>>3)&63, kt = (idx>>9)&7, t = (idx>>12)&1, g = (idx>>13)&3, w = idx>>15;
    int r = lane & 15, q = lane >> 4;
    int jj = w*32 + t*16 + r, k = kt*32 + q*8 + e;
    whh1p[idx] = (jj<250 && k<250) ? ldb(whh1, (size_t)(g*250+jj)*250 + k, f) : 0;
    return;
  }
  idx -= R_W256;
  if (idx < R_WD)   { int n = idx/256, k = idx%256; wdp[idx] = (n<45 && k<250) ? ldb(dw, (size_t)n*250+k, f) : 0; return; }
  idx -= R_WD;
  if (idx < 1024) { bias0[idx] = (idx<1000) ? ldf(bih0, idx, f) + ldf(bhh0, idx, f) : 0.f; return; }
  idx -= 1024;
  if (idx < 1024) { bias1[idx] = (idx<1000) ? ldf(bih1, idx, f) + ldf(bhh1, idx, f) : 0.f; return; }
  idx -= 1024;
  if (idx < 128)  { biasd[idx] = (idx<45) ? ldf(db, idx, f) : 0.f; }
}

// ---------------- char conv + max + word-emb concat -> emb [32768][288] bf16 ----------------
__global__ void embed_conv(const int* __restrict__ ci, const int* __restrict__ wi,
                           const void* __restrict__ cemb,
                           const void* __restrict__ wemb,
                           const void* __restrict__ cw,
                           const void* __restrict__ cb,
                           unsigned short* __restrict__ emb,
                           const int* __restrict__ flagp)
{
  __shared__ float s_cw[960];
  __shared__ float s_cb[32];
  __shared__ float s_ce[1000];
  __shared__ int   s_ind[4][12];
  __shared__ float s_ct[4][120];
  const int f = *flagp;
  const int tid = threadIdx.x;
  for (int i = tid; i < 960; i += 256) s_cw[i] = ldf(cw, i, f);
  if (tid < 32) s_cb[tid] = ldf(cb, tid, f);
  for (int i = tid; i < 1000; i += 256) s_ce[i] = ldf(cemb, i, f);
  __syncthreads();
  const int wv = tid >> 6, lane = tid & 63;
  const int tok = blockIdx.x * 4 + wv;
  if (lane < 12) s_ind[wv][lane] = ci[tok*12 + lane];
  __syncthreads();
#pragma unroll
  for (int p = 0; p < 2; ++p) {
    int pos = p*64 + lane;
    if (pos < 120) {
      int w = pos / 10, ce = pos % 10;
      s_ct[wv][pos] = s_ce[s_ind[wv][w]*10 + ce];
    }
  }
  __syncthreads();
  if (lane < 32) {
    const int ff = lane;
    float mx = -1e30f;
    for (int p = 0; p < Ww; ++p) {
      float acc = s_cb[ff];
#pragma unroll
      for (int k = 0; k < 3; ++k) {
        int wp = p + k - 1;
        if (wp >= 0 && wp < Ww) {
#pragma unroll
          for (int ce = 0; ce < CEe; ++ce)
            acc += s_ct[wv][wp*10 + ce] * s_cw[ff*30 + ce*3 + k];
        }
      }
      mx = fmaxf(mx, acc);
    }
    emb[(size_t)tok*KP0 + ff] = f2bu(mx);
  }
  const int widx = wi[tok];
  for (int j = lane; j < 250; j += 64)
    emb[(size_t)tok*KP0 + Ff + j] = ldb(wemb, (size_t)widx*250 + j, f);
  if (lane >= 58) emb[(size_t)tok*KP0 + 282 + (lane - 58)] = 0;
}

// ---------------- bf16 MFMA GEMM: C[r][n] = sum_k A[r][k]*W[n][k] + bias[n] ----------------
template<int KC>
__global__ __launch_bounds__(256, 2) void gemm_bf16(
    const unsigned short* __restrict__ A, int lda,
    const unsigned short* __restrict__ Bw,
    const float* __restrict__ bias,
    void* __restrict__ Cout, int ldo, int nvalid,
    const int* __restrict__ flagp, int useflag, int gate_pad)
{
  __shared__ alignas(16) unsigned short lsA[128*32];
  __shared__ alignas(16) unsigned short lsB[128*32];
  const int tid = threadIdx.x;
  const int lane = tid & 63;
  const int w = tid >> 6;
  const int wr = w >> 1, wc = w & 1;
  const int mt = blockIdx.x, nt = blockIdx.y;

  f32x4 acc[4][4];
#pragma unroll
  for (int m = 0; m < 4; ++m)
#pragma unroll
    for (int n = 0; n < 4; ++n) acc[m][n] = (f32x4){0.f,0.f,0.f,0.f};

  for (int kt = 0; kt < KC; ++kt) {
    __syncthreads();
#pragma unroll
    for (int p = 0; p < 2; ++p) {
      int flat = p*256 + tid;
      int row = flat >> 2, c = flat & 3;
      *(bf16x8*)&lsA[flat*8] = *(const bf16x8*)(A  + (size_t)(mt*128 + row)*lda     + kt*32 + c*8);
      *(bf16x8*)&lsB[flat*8] = *(const bf16x8*)(Bw + (size_t)(nt*128 + row)*(KC*32) + kt*32 + c*8);
    }
    __syncthreads();
    bf16x8 a[4], b[4];
#pragma unroll
    for (int m = 0; m < 4; ++m) {
      int row = wr*64 + m*16 + (lane & 15);
      a[m] = *(const bf16x8*)&lsA[row*32 + (lane >> 4)*8];
    }
#pragma unroll
    for (int n = 0; n < 4; ++n) {
      int row = wc*64 + n*16 + (lane & 15);
      b[n] = *(const bf16x8*)&lsB[row*32 + (lane >> 4)*8];
    }
#pragma unroll
    for (int m = 0; m < 4; ++m)
#pragma unroll
      for (int n = 0; n < 4; ++n)
        acc[m][n] = __builtin_amdgcn_mfma_f32_16x16x32_bf16(a[m], b[n], acc[m][n], 0, 0, 0);
  }

  const bool of32 = useflag && (*flagp != 0);
  const int rbase = mt*128 + wr*64;
  const int cbase = nt*128 + wc*64;
#pragma unroll
  for (int m = 0; m < 4; ++m)
#pragma unroll
    for (int n = 0; n < 4; ++n) {
      int col = cbase + n*16 + (lane & 15);
      if (col < nvalid) {
        float bv = bias[col];
        int colw = col;
        if (gate_pad) {
          int g = (col>=250) + (col>=500) + (col>=750);
          colw = col + 6*g;
        }
#pragma unroll
        for (int j = 0; j < 4; ++j) {
          int row = rbase + m*16 + (lane >> 4)*4 + j;
          float val = acc[m][n][j] + bv;
          if (of32) ((float*)Cout)[(size_t)row*ldo + colw] = val;
          else      ((unsigned short*)Cout)[(size_t)row*ldo + colw] = f2bu(val);
        }
      }
    }
}

// ---------------- COMPACT 16-wave LSTM: replicated-batch in-register pointwise ------------
// xg: [32768][1024] bf16, cols gate-padded. whh: coalesced-packed (see prep).
// hout: [32768][256] bf16 (cols 250..255 zeroed). h_s rows replicated: row i = batch i>>2
// -> MFMA C-row q*4 (acc[g][0], static) = batch q at lane (r,q); pointwise on ALL lanes,
// scalar c_reg per lane. h written only to LDS; hout stored by coalesced copy phase
// overlapped into the NEXT step (parity dbuf). One barrier/step. NRES=7 LDS residency.
__global__ __launch_bounds__(1024) void lstm_c(
    const unsigned short* __restrict__ xg,
    const unsigned short* __restrict__ whh,
    unsigned short* __restrict__ hout)
{
  __shared__ alignas(16) unsigned short whl[16*NRES*64*8];  // 112 KB resident whh
  __shared__ alignas(16) unsigned short h_s[2][16*256];     // parity dbuf; row i = batch i>>2
  __shared__ alignas(16) unsigned short xg_l[2][NB*XPAD];   // dbuf
  const int tid = threadIdx.x;
  const int lane = tid & 63;
  const int w = tid >> 6;                                   // 0..15
  const int r = lane & 15, q = lane >> 4;
  const int bb0 = blockIdx.x * NB;
  const unsigned short* wbase = whh + (size_t)(w >> 1)*32768 + (size_t)(w & 1)*4096 + lane*8;
  const int col = w*16 + r;                                 // this lane's within-gate col
  const int c8 = col >> 3, ce = col & 7;                    // chunk / elem of col

  // one-time: resident fragments (g=0, kt=0..6) -> LDS, lane-contiguous layout
#pragma unroll
  for (int f = 0; f < NRES; ++f)
    *(bf16x8*)&whl[((w*NRES + f)*64 + lane)*8] = *(const bf16x8*)(wbase + f*512);

  for (int i = tid; i < 2*16*256; i += 1024) ((unsigned short*)h_s)[i] = 0;
  float c_reg = 0.f;                                        // cell state: (batch q, col)
  if (tid < NB*128) {
    int row = tid >> 7, ch = tid & 127;
    *(bf16x8*)&xg_l[0][row*XPAD + ch*8] =
        *(const bf16x8*)(xg + (size_t)(bb0 + row)*1024 + ch*8);
  }
  __syncthreads();

  int cur = 0;
#pragma unroll 1
  for (int s = 0; s < Ss; ++s) {
    const int par = s & 1;
    // overlapped copy phase: step s-1's h (in h_s[par]) -> hout, coalesced b128
    if (s > 0 && tid < 128) {
      int b = tid >> 5, cc = tid & 31;
      int row = 4*b;
      bf16x8 hv = *(const bf16x8*)&h_s[par][row*256 + ((cc ^ (row & 7)) << 3)];
      *(bf16x8*)(hout + (size_t)((s-1)*512 + bb0 + b)*256 + cc*8) = hv;
    }
    // prefetch next step's xg (staged to LDS after pointwise)
    const int sp = (s + 1 < Ss) ? s + 1 : s;
    bf16x8 pf;
    if (tid < NB*128) {
      int row = tid >> 7, ch = tid & 127;
      pf = *(const bf16x8*)(xg + (size_t)(sp*512 + bb0 + row)*1024 + ch*8);
    }
    // A fragments (h_prev from parity buffer; rows replicated batch row>>2)
    bf16x8 av[8];
#pragma unroll
    for (int kt = 0; kt < 8; ++kt) {
      int ch = (kt*4 + q) ^ (r & 7);
      av[kt] = *(const bf16x8*)&h_s[par][r*256 + ch*8];
    }
    // 4 gate tiles, fully unrolled; g=0: NRES LDS + 1 global
    f32x4 acc[4];
#pragma unroll
    for (int g = 0; g < 4; ++g) acc[g] = (f32x4){0.f,0.f,0.f,0.f};
#pragma unroll
    for (int kt = 0; kt < NRES; ++kt) {
      bf16x8 bv = *(const bf16x8*)&whl[((w*NRES + kt)*64 + lane)*8];
      acc[0] = __builtin_amdgcn_mfma_f32_16x16x32_bf16(av[kt], bv, acc[0], 0, 0, 0);
    }
    {
      bf16x8 bv = *(const bf16x8*)(wbase + 7*512);
      acc[0] = __builtin_amdgcn_mfma_f32_16x16x32_bf16(av[7], bv, acc[0], 0, 0, 0);
    }
#pragma unroll
    for (int g = 1; g < 4; ++g) {
      const unsigned short* bp = wbase + g*8192;
#pragma unroll
      for (int kt = 0; kt < 8; ++kt) {
        bf16x8 bv = *(const bf16x8*)(bp + kt*512);
        acc[g] = __builtin_amdgcn_mfma_f32_16x16x32_bf16(av[kt], bv, acc[g], 0, 0, 0);
      }
    }
    // in-register pointwise, ALL lanes: lane (r,q) owns (batch q, col); acc[g][0] is batch q
    {
      const unsigned short* xc = &xg_l[cur][q*XPAD];
      float gi = acc[0][0] + bu2f(xc[col]);
      float gf = acc[1][0] + bu2f(xc[256 + col]);
      float gg = acc[2][0] + bu2f(xc[512 + col]);
      float go = acc[3][0] + bu2f(xc[768 + col]);
      float c = sigm(gf)*c_reg + sigm(gi)*tanh_f(gg);
      float h = sigm(go)*tanh_f(c);
      if (col >= Hh) { c = 0.f; h = 0.f; }
      c_reg = c;
      unsigned short hb = f2bu(h);
      // write h to the 4 replicated rows of next parity buffer (swizzled per row)
#pragma unroll
      for (int i = 0; i < 4; ++i) {
        int row = 4*q + i;
        h_s[par ^ 1][row*256 + ((c8 ^ (row & 7)) << 3) + ce] = hb;
      }
    }
    // stage prefetched xg into the other buffer
    if (tid < NB*128) {
      int row = tid >> 7, ch = tid & 127;
      *(bf16x8*)&xg_l[cur ^ 1][row*XPAD + ch*8] = pf;
    }
    __syncthreads();   // ONE barrier: h_s[par^1], xg_l[cur^1] ready; all reads of par done
    cur ^= 1;
  }
  // final copy: step Ss-1's h is in h_s[Ss&1] = h_s[0]
  if (tid < 128) {
    int b = tid >> 5, cc = tid & 31;
    int row = 4*b;
    bf16x8 hv = *(const bf16x8*)&h_s[Ss & 1][row*256 + ((cc ^ (row & 7)) << 3)];
    *(bf16x8*)(hout + (size_t)((Ss-1)*512 + bb0 + b)*256 + cc*8) = hv;
  }
}

// ---------------- launcher ----------------
extern "C" void kernel_launch(void* const* d_in, const int* in_sizes, int n_in,
                              void* d_out, int out_size, void* d_ws, size_t ws_size,
                              hipStream_t stream) {
  (void)in_sizes; (void)n_in; (void)out_size;
  const int* ci = (const int*)d_in[0];
  const int* wi = (const int*)d_in[1];
  const void* cemb = d_in[2];
  const void* wemb = d_in[3];
  const void* cw   = d_in[4];
  const void* cb   = d_in[5];
  const void* wih0 = d_in[6];
  const void* whh0 = d_in[7];
  const void* bih0 = d_in[8];
  const void* bhh0 = d_in[9];
  const void* wih1 = d_in[10];
  const void* whh1 = d_in[11];
  const void* bih1 = d_in[12];
  const void* bhh1 = d_in[13];
  const void* dw   = d_in[14];
  const void* db   = d_in[15];

  // ws layout (bytes), weights first; total = 105,000,960
  constexpr size_t OFF_WIH0 = 0;
  constexpr size_t OFF_WIH1 = OFF_WIH0 + 589824;
  constexpr size_t OFF_WHH0 = OFF_WIH1 + 524288;
  constexpr size_t OFF_WHH1 = OFF_WHH0 + 524288;
  constexpr size_t OFF_WD   = OFF_WHH1 + 524288;
  constexpr size_t OFF_B0   = OFF_WD   + 65536;
  constexpr size_t OFF_B1   = OFF_B0   + 4096;
  constexpr size_t OFF_BD   = OFF_B1   + 4096;
  constexpr size_t OFF_FLAG = OFF_BD   + 2048;
  constexpr size_t OFF_H1   = OFF_BD   + 4096;
  constexpr size_t OFF_EMB  = OFF_H1   + 16777216;
  constexpr size_t OFF_XG   = OFF_EMB  + 18874368;
  constexpr size_t WS_NEED  = OFF_XG   + 67108864;
  if (ws_size < WS_NEED) return;

  char* ws = (char*)d_ws;
  unsigned short* WIH0 = (unsigned short*)(ws + OFF_WIH0);
  unsigned short* WIH1 = (unsigned short*)(ws + OFF_WIH1);
  unsigned short* WHH0 = (unsigned short*)(ws + OFF_WHH0);
  unsigned short* WHH1 = (unsigned short*)(ws + OFF_WHH1);
  unsigned short* WD   = (unsigned short*)(ws + OFF_WD);
  float* B0 = (float*)(ws + OFF_B0);
  float* B1 = (float*)(ws + OFF_B1);
  float* BD = (float*)(ws + OFF_BD);
  int* FLAG = (int*)(ws + OFF_FLAG);
  unsigned short* H1   = (unsigned short*)(ws + OFF_H1);
  unsigned short* EMB  = (unsigned short*)(ws + OFF_EMB);
  unsigned short* H2   = (unsigned short*)(ws + OFF_EMB);  // alias: EMB dead after xg0 gemm
  unsigned short* XG   = (unsigned short*)(ws + OFF_XG);

  detect_dtype<<<1, 64, 0, stream>>>((const unsigned short*)wemb, FLAG);
  prep_weights<<<(PREP_TOTAL + 255)/256, 256, 0, stream>>>(
      wih0, wih1, whh0, whh1, dw, bih0, bhh0, bih1, bhh1, db,
      WIH0, WIH1, WHH0, WHH1, WD, B0, B1, BD, FLAG);
  embed_conv<<<Mtok/4, 256, 0, stream>>>(ci, wi, cemb, wemb, cw, cb, EMB, FLAG);
  gemm_bf16<9><<<dim3(Mtok/128, NGP/128), 256, 0, stream>>>(EMB, KP0, WIH0, B0, XG, NGP, NGP, FLAG, 0, 1);
  lstm_c<<<NBLK, 1024, 0, stream>>>(XG, WHH0, H1);
  gemm_bf16<8><<<dim3(Mtok/128, NGP/128), 256, 0, stream>>>(H1, KP1, WIH1, B1, XG, NGP, NGP, FLAG, 0, 1);
  lstm_c<<<NBLK, 1024, 0, stream>>>(XG, WHH1, H2);
  gemm_bf16<8><<<dim3(Mtok/128, 1), 256, 0, stream>>>(H2, KP1, WD, BD, d_out, Tt, Tt, FLAG, 1, 0);
}

// Round 19
// 669.036 us; speedup vs baseline: 1.5019x; 1.2437x over previous
//
#include <hip/hip_runtime.h>
#include <hip/hip_bf16.h>

// POS tagger forward: char-conv word features + word emb -> 2-layer LSTM (H=250) -> dense(45)
// B=512, S=64.
//
// ROUND 19: exact revert to round-16 (best verified: 669us total, lstm 287us/dispatch).
// Rounds 17/18 (in-register pointwise variants) both regressed (452/366us) via extra memory
// traffic; round 14/15 (cross-XCD weight residency) measured 74us/step sync cost. Round-16
// runs the per-step whh stream at ~87% of the per-CU L2->L1 port ceiling -> structural floor.
// 128 blocks x 4 batches, NRES=7 whh fragments LDS-resident, rolled I$-safe loop body.

#define Bb 512
#define Ss 64
#define Ww 12
#define Tt 45
#define CEe 10
#define Ff 32
#define Hh 250
#define Mtok (Bb*Ss)      // 32768
#define KP0 288           // 282 padded to 9*32
#define KP1 256           // 250 padded to 8*32
#define NGP 1024          // gates padded: 4 sections of 256
#define XPAD 1036         // xg LDS row stride (bank-spread)
#define NB 4              // batches per LSTM block
#define NBLK (Bb/NB)      // 128 LSTM blocks
#define NRES 7            // resident whh fragments per wave (of 32)

typedef float f32x4 __attribute__((ext_vector_type(4)));
typedef __bf16 bf16x8 __attribute__((ext_vector_type(8)));

__device__ inline unsigned short f2bu(float f) {
  return __builtin_bit_cast(unsigned short, __float2bfloat16(f));
}
__device__ inline float bu2f(unsigned short u) {
  return __bfloat162float(__builtin_bit_cast(__hip_bfloat16, u));
}
__device__ inline float sigm(float x) { return 1.f / (1.f + __expf(-x)); }
__device__ inline float tanh_f(float x) { float e = __expf(2.f*x); return 1.f - 2.f/(e+1.f); }

// dtype-adaptive loads: f32flag ? float data : bf16(u16) data
__device__ inline float ldf(const void* p, size_t i, int f32) {
  return f32 ? ((const float*)p)[i] : bu2f(((const unsigned short*)p)[i]);
}
__device__ inline unsigned short ldb(const void* p, size_t i, int f32) {
  return f32 ? f2bu(((const float*)p)[i]) : ((const unsigned short*)p)[i];
}

// ---------------- dtype detection ----------------
__global__ void detect_dtype(const unsigned short* __restrict__ wemb_u16, int* __restrict__ flag) {
  if (threadIdx.x == 0) {
    int cnt = 0;
    for (int i = 0; i < 64; ++i) {
      unsigned short v = wemb_u16[2*i];
      int e = (v >> 7) & 0xFF;
      cnt += (e >= 127) ? 1 : 0;
    }
    *flag = (cnt > 0) ? 1 : 0;
  }
}

// ---------------- weight prep ----------------
// wih*: rows 0..999 orig order (+pad to 1024x{288,256}).
// whh*: packed for coalesced wave loads: idx = ((((w8*4+g)*2+t)*8+kt)*64+lane)*8+e
//       <- orig whh[g*250 + (w8*32+t*16+(lane&15))][kt*32 + (lane>>4)*8 + e]  (0-pad invalid)
#define R_WIH0 (1024*288)
#define R_W256 (1024*256)
#define R_WD   (128*256)
#define PREP_TOTAL (R_WIH0 + 3*R_W256 + R_WD + 1024 + 1024 + 128)

__global__ void prep_weights(const void* __restrict__ wih0, const void* __restrict__ wih1,
                             const void* __restrict__ whh0, const void* __restrict__ whh1,
                             const void* __restrict__ dw,
                             const void* __restrict__ bih0, const void* __restrict__ bhh0,
                             const void* __restrict__ bih1, const void* __restrict__ bhh1,
                             const void* __restrict__ db,
                             unsigned short* __restrict__ wih0p, unsigned short* __restrict__ wih1p,
                             unsigned short* __restrict__ whh0p, unsigned short* __restrict__ whh1p,
                             unsigned short* __restrict__ wdp,
                             float* __restrict__ bias0, float* __restrict__ bias1, float* __restrict__ biasd,
                             const int* __restrict__ flagp)
{
  const int f = *flagp;
  int idx = blockIdx.x * 256 + threadIdx.x;
  if (idx < R_WIH0) {
    int n = idx / 288, k = idx % 288;
    wih0p[idx] = (n < 1000 && k < 282) ? ldb(wih0, (size_t)n*282 + k, f) : 0;
    return;
  }
  idx -= R_WIH0;
  if (idx < R_W256) { int n = idx/256, k = idx%256; wih1p[idx] = (n<1000 && k<250) ? ldb(wih1, (size_t)n*250+k, f) : 0; return; }
  idx -= R_W256;
  if (idx < R_W256) {  // whh0 coalesced-pack [w8][g][t][kt][lane][8]
    int e = idx & 7, lane = (idx>>3)&63, kt = (idx>>9)&7, t = (idx>>12)&1, g = (idx>>13)&3, w = idx>>15;
    int r = lane & 15, q = lane >> 4;
    int jj = w*32 + t*16 + r, k = kt*32 + q*8 + e;
    whh0p[idx] = (jj<250 && k<250) ? ldb(whh0, (size_t)(g*250+jj)*250 + k, f) : 0;
    return;
  }
  idx -= R_W256;
  if (idx < R_W256) {  // whh1 coalesced-pack
    int e = idx & 7, lane = (idx>>3)&63, kt = (idx>>9)&7, t = (idx>>12)&1, g = (idx>>13)&3, w = idx>>15;
    int r = lane & 15, q = lane >> 4;
    int jj = w*32 + t*16 + r, k = kt*32 + q*8 + e;
    whh1p[idx] = (jj<250 && k<250) ? ldb(whh1, (size_t)(g*250+jj)*250 + k, f) : 0;
    return;
  }
  idx -= R_W256;
  if (idx < R_WD)   { int n = idx/256, k = idx%256; wdp[idx] = (n<45 && k<250) ? ldb(dw, (size_t)n*250+k, f) : 0; return; }
  idx -= R_WD;
  if (idx < 1024) { bias0[idx] = (idx<1000) ? ldf(bih0, idx, f) + ldf(bhh0, idx, f) : 0.f; return; }
  idx -= 1024;
  if (idx < 1024) { bias1[idx] = (idx<1000) ? ldf(bih1, idx, f) + ldf(bhh1, idx, f) : 0.f; return; }
  idx -= 1024;
  if (idx < 128)  { biasd[idx] = (idx<45) ? ldf(db, idx, f) : 0.f; }
}

// ---------------- char conv + max + word-emb concat -> emb [32768][288] bf16 ----------------
__global__ void embed_conv(const int* __restrict__ ci, const int* __restrict__ wi,
                           const void* __restrict__ cemb,
                           const void* __restrict__ wemb,
                           const void* __restrict__ cw,
                           const void* __restrict__ cb,
                           unsigned short* __restrict__ emb,
                           const int* __restrict__ flagp)
{
  __shared__ float s_cw[960];
  __shared__ float s_cb[32];
  __shared__ float s_ce[1000];
  __shared__ int   s_ind[4][12];
  __shared__ float s_ct[4][120];
  const int f = *flagp;
  const int tid = threadIdx.x;
  for (int i = tid; i < 960; i += 256) s_cw[i] = ldf(cw, i, f);
  if (tid < 32) s_cb[tid] = ldf(cb, tid, f);
  for (int i = tid; i < 1000; i += 256) s_ce[i] = ldf(cemb, i, f);
  __syncthreads();
  const int wv = tid >> 6, lane = tid & 63;
  const int tok = blockIdx.x * 4 + wv;
  if (lane < 12) s_ind[wv][lane] = ci[tok*12 + lane];
  __syncthreads();
#pragma unroll
  for (int p = 0; p < 2; ++p) {
    int pos = p*64 + lane;
    if (pos < 120) {
      int w = pos / 10, ce = pos % 10;
      s_ct[wv][pos] = s_ce[s_ind[wv][w]*10 + ce];
    }
  }
  __syncthreads();
  if (lane < 32) {
    const int ff = lane;
    float mx = -1e30f;
    for (int p = 0; p < Ww; ++p) {
      float acc = s_cb[ff];
#pragma unroll
      for (int k = 0; k < 3; ++k) {
        int wp = p + k - 1;
        if (wp >= 0 && wp < Ww) {
#pragma unroll
          for (int ce = 0; ce < CEe; ++ce)
            acc += s_ct[wv][wp*10 + ce] * s_cw[ff*30 + ce*3 + k];
        }
      }
      mx = fmaxf(mx, acc);
    }
    emb[(size_t)tok*KP0 + ff] = f2bu(mx);
  }
  const int widx = wi[tok];
  for (int j = lane; j < 250; j += 64)
    emb[(size_t)tok*KP0 + Ff + j] = ldb(wemb, (size_t)widx*250 + j, f);
  if (lane >= 58) emb[(size_t)tok*KP0 + 282 + (lane - 58)] = 0;
}

// ---------------- bf16 MFMA GEMM: C[r][n] = sum_k A[r][k]*W[n][k] + bias[n] ----------------
template<int KC>
__global__ __launch_bounds__(256, 2) void gemm_bf16(
    const unsigned short* __restrict__ A, int lda,
    const unsigned short* __restrict__ Bw,
    const float* __restrict__ bias,
    void* __restrict__ Cout, int ldo, int nvalid,
    const int* __restrict__ flagp, int useflag, int gate_pad)
{
  __shared__ alignas(16) unsigned short lsA[128*32];
  __shared__ alignas(16) unsigned short lsB[128*32];
  const int tid = threadIdx.x;
  const int lane = tid & 63;
  const int w = tid >> 6;
  const int wr = w >> 1, wc = w & 1;
  const int mt = blockIdx.x, nt = blockIdx.y;

  f32x4 acc[4][4];
#pragma unroll
  for (int m = 0; m < 4; ++m)
#pragma unroll
    for (int n = 0; n < 4; ++n) acc[m][n] = (f32x4){0.f,0.f,0.f,0.f};

  for (int kt = 0; kt < KC; ++kt) {
    __syncthreads();
#pragma unroll
    for (int p = 0; p < 2; ++p) {
      int flat = p*256 + tid;
      int row = flat >> 2, c = flat & 3;
      *(bf16x8*)&lsA[flat*8] = *(const bf16x8*)(A  + (size_t)(mt*128 + row)*lda     + kt*32 + c*8);
      *(bf16x8*)&lsB[flat*8] = *(const bf16x8*)(Bw + (size_t)(nt*128 + row)*(KC*32) + kt*32 + c*8);
    }
    __syncthreads();
    bf16x8 a[4], b[4];
#pragma unroll
    for (int m = 0; m < 4; ++m) {
      int row = wr*64 + m*16 + (lane & 15);
      a[m] = *(const bf16x8*)&lsA[row*32 + (lane >> 4)*8];
    }
#pragma unroll
    for (int n = 0; n < 4; ++n) {
      int row = wc*64 + n*16 + (lane & 15);
      b[n] = *(const bf16x8*)&lsB[row*32 + (lane >> 4)*8];
    }
#pragma unroll
    for (int m = 0; m < 4; ++m)
#pragma unroll
      for (int n = 0; n < 4; ++n)
        acc[m][n] = __builtin_amdgcn_mfma_f32_16x16x32_bf16(a[m], b[n], acc[m][n], 0, 0, 0);
  }

  const bool of32 = useflag && (*flagp != 0);
  const int rbase = mt*128 + wr*64;
  const int cbase = nt*128 + wc*64;
#pragma unroll
  for (int m = 0; m < 4; ++m)
#pragma unroll
    for (int n = 0; n < 4; ++n) {
      int col = cbase + n*16 + (lane & 15);
      if (col < nvalid) {
        float bv = bias[col];
        int colw = col;
        if (gate_pad) {
          int g = (col>=250) + (col>=500) + (col>=750);
          colw = col + 6*g;
        }
#pragma unroll
        for (int j = 0; j < 4; ++j) {
          int row = rbase + m*16 + (lane >> 4)*4 + j;
          float val = acc[m][n][j] + bv;
          if (of32) ((float*)Cout)[(size_t)row*ldo + colw] = val;
          else      ((unsigned short*)Cout)[(size_t)row*ldo + colw] = f2bu(val);
        }
      }
    }
}

// ---------------- COMPACT 16-wave LSTM, 128 blocks x 4 batches, partial whh residency ------
// xg: [32768][1024] bf16, cols gate-padded. whh: coalesced-packed (see prep).
// hout: [32768][256] bf16 (cols 250..255 zeroed). Wave w owns within-gate cols
// [w*16,w*16+16) for all 4 gates; its 32 1KB fragments: g*8192+kt*512 off wbase.
// First NRES=7 fragments (g=0, kt=0..6) live in LDS (112 KB, filled once) -> per-step
// global stream drops 512->400 KB. 1 block/CU (160 KB LDS). Round-13 loop body otherwise.
__global__ __launch_bounds__(1024) void lstm_c(
    const unsigned short* __restrict__ xg,
    const unsigned short* __restrict__ whh,
    unsigned short* __restrict__ hout)
{
  __shared__ alignas(16) unsigned short whl[16*NRES*64*8];  // 112 KB resident whh
  __shared__ alignas(16) unsigned short h_s[16*256];        // swizzled chunk^(b&7); rows>=NB zero
  __shared__ alignas(16) unsigned short xg_l[2][NB*XPAD];   // dbuf
  __shared__ float g_s[NB][1028];                           // f32 gate pre-acts
  __shared__ float c_s[NB][260];                            // f32 cell state
  const int tid = threadIdx.x;
  const int lane = tid & 63;
  const int w = tid >> 6;                                   // 0..15
  const int r = lane & 15, q = lane >> 4;
  const int bb0 = blockIdx.x * NB;
  const unsigned short* wbase = whh + (size_t)(w >> 1)*32768 + (size_t)(w & 1)*4096 + lane*8;

  // one-time: resident fragments (g=0, kt=0..6) -> LDS, lane-contiguous layout
#pragma unroll
  for (int f = 0; f < NRES; ++f)
    *(bf16x8*)&whl[((w*NRES + f)*64 + lane)*8] = *(const bf16x8*)(wbase + f*512);

  for (int i = tid; i < 16*256; i += 1024) h_s[i] = 0;
  for (int i = tid; i < NB*260; i += 1024) ((float*)c_s)[i] = 0.f;
  if (tid < NB*128) {
    int row = tid >> 7, ch = tid & 127;
    *(bf16x8*)&xg_l[0][row*XPAD + ch*8] =
        *(const bf16x8*)(xg + (size_t)(bb0 + row)*1024 + ch*8);
  }
  __syncthreads();

  int cur = 0;
#pragma unroll 1
  for (int s = 0; s < Ss; ++s) {
    // prefetch next step's xg (consumed after the mid barrier)
    const int sp = (s + 1 < Ss) ? s + 1 : s;
    bf16x8 pf;
    if (tid < NB*128) {
      int row = tid >> 7, ch = tid & 127;
      pf = *(const bf16x8*)(xg + (size_t)(sp*512 + bb0 + row)*1024 + ch*8);
    }
    // A fragments (h_prev, swizzle-matched; rows >= NB are zeros)
    bf16x8 av[8];
#pragma unroll
    for (int kt = 0; kt < 8; ++kt) {
      int ch = (kt*4 + q) ^ (r & 7);
      av[kt] = *(const bf16x8*)&h_s[r*256 + ch*8];
    }
    // phase A, g=0 tile: 7 LDS-resident fragments + 1 streamed
    {
      f32x4 a = (f32x4){0.f,0.f,0.f,0.f};
#pragma unroll
      for (int kt = 0; kt < NRES; ++kt) {
        bf16x8 bv = *(const bf16x8*)&whl[((w*NRES + kt)*64 + lane)*8];
        a = __builtin_amdgcn_mfma_f32_16x16x32_bf16(av[kt], bv, a, 0, 0, 0);
      }
      {
        bf16x8 bv = *(const bf16x8*)(wbase + 7*512);
        a = __builtin_amdgcn_mfma_f32_16x16x32_bf16(av[7], bv, a, 0, 0, 0);
      }
      if (q == 0) {
        const int gcol = (w << 4) + r;
#pragma unroll
        for (int j = 0; j < 4; ++j) g_s[j][gcol] = a[j];
      }
    }
    // phase A, g=1..3: fully streamed (rolled)
#pragma unroll 1
    for (int g = 1; g < 4; ++g) {
      const unsigned short* bp = wbase + g*8192;
      f32x4 a = (f32x4){0.f,0.f,0.f,0.f};
#pragma unroll
      for (int kt = 0; kt < 8; ++kt) {
        bf16x8 bv = *(const bf16x8*)(bp + kt*512);
        a = __builtin_amdgcn_mfma_f32_16x16x32_bf16(av[kt], bv, a, 0, 0, 0);
      }
      if (q == 0) {
        const int gcol = g*256 + (w << 4) + r;
#pragma unroll
        for (int j = 0; j < 4; ++j) g_s[j][gcol] = a[j];
      }
    }
    __syncthreads();   // B1: g_s ready; all av/xg_l[cur] reads complete
    // phase B: pointwise, exactly 1024 (b,j) pairs -> one per thread
    {
      const unsigned short* xc = &xg_l[cur][0];
      const int b = tid >> 8, j = tid & 255;
      float gi = g_s[b][j]       + bu2f(xc[b*XPAD + j]);
      float gf = g_s[b][256 + j] + bu2f(xc[b*XPAD + 256 + j]);
      float gg = g_s[b][512 + j] + bu2f(xc[b*XPAD + 512 + j]);
      float go = g_s[b][768 + j] + bu2f(xc[b*XPAD + 768 + j]);
      float c = sigm(gf)*c_s[b][j] + sigm(gi)*tanh_f(gg);
      float h = sigm(go)*tanh_f(c);
      if (j >= Hh) { c = 0.f; h = 0.f; }
      c_s[b][j] = c;
      unsigned short hb = f2bu(h);
      h_s[b*256 + (((j >> 3) ^ (b & 7)) << 3) + (j & 7)] = hb;
      hout[(size_t)(s*512 + bb0 + b)*256 + j] = hb;
    }
    // stage prefetched xg into the other buffer
    if (tid < NB*128) {
      int row = tid >> 7, ch = tid & 127;
      *(bf16x8*)&xg_l[cur ^ 1][row*XPAD + ch*8] = pf;
    }
    __syncthreads();   // B2: h_s, c_s, xg_l[cur^1] visible for next step
    cur ^= 1;
  }
}

// ---------------- launcher ----------------
extern "C" void kernel_launch(void* const* d_in, const int* in_sizes, int n_in,
                              void* d_out, int out_size, void* d_ws, size_t ws_size,
                              hipStream_t stream) {
  (void)in_sizes; (void)n_in; (void)out_size;
  const int* ci = (const int*)d_in[0];
  const int* wi = (const int*)d_in[1];
  const void* cemb = d_in[2];
  const void* wemb = d_in[3];
  const void* cw   = d_in[4];
  const void* cb   = d_in[5];
  const void* wih0 = d_in[6];
  const void* whh0 = d_in[7];
  const void* bih0 = d_in[8];
  const void* bhh0 = d_in[9];
  const void* wih1 = d_in[10];
  const void* whh1 = d_in[11];
  const void* bih1 = d_in[12];
  const void* bhh1 = d_in[13];
  const void* dw   = d_in[14];
  const void* db   = d_in[15];

  // ws layout (bytes), weights first; total = 105,000,960
  constexpr size_t OFF_WIH0 = 0;
  constexpr size_t OFF_WIH1 = OFF_WIH0 + 589824;
  constexpr size_t OFF_WHH0 = OFF_WIH1 + 524288;
  constexpr size_t OFF_WHH1 = OFF_WHH0 + 524288;
  constexpr size_t OFF_WD   = OFF_WHH1 + 524288;
  constexpr size_t OFF_B0   = OFF_WD   + 65536;
  constexpr size_t OFF_B1   = OFF_B0   + 4096;
  constexpr size_t OFF_BD   = OFF_B1   + 4096;
  constexpr size_t OFF_FLAG = OFF_BD   + 2048;
  constexpr size_t OFF_H1   = OFF_BD   + 4096;
  constexpr size_t OFF_EMB  = OFF_H1   + 16777216;
  constexpr size_t OFF_XG   = OFF_EMB  + 18874368;
  constexpr size_t WS_NEED  = OFF_XG   + 67108864;
  if (ws_size < WS_NEED) return;

  char* ws = (char*)d_ws;
  unsigned short* WIH0 = (unsigned short*)(ws + OFF_WIH0);
  unsigned short* WIH1 = (unsigned short*)(ws + OFF_WIH1);
  unsigned short* WHH0 = (unsigned short*)(ws + OFF_WHH0);
  unsigned short* WHH1 = (unsigned short*)(ws + OFF_WHH1);
  unsigned short* WD   = (unsigned short*)(ws + OFF_WD);
  float* B0 = (float*)(ws + OFF_B0);
  float* B1 = (float*)(ws + OFF_B1);
  float* BD = (float*)(ws + OFF_BD);
  int* FLAG = (int*)(ws + OFF_FLAG);
  unsigned short* H1   = (unsigned short*)(ws + OFF_H1);
  unsigned short* EMB  = (unsigned short*)(ws + OFF_EMB);
  unsigned short* H2   = (unsigned short*)(ws + OFF_EMB);  // alias: EMB dead after xg0 gemm
  unsigned short* XG   = (unsigned short*)(ws + OFF_XG);

  detect_dtype<<<1, 64, 0, stream>>>((const unsigned short*)wemb, FLAG);
  prep_weights<<<(PREP_TOTAL + 255)/256, 256, 0, stream>>>(
      wih0, wih1, whh0, whh1, dw, bih0, bhh0, bih1, bhh1, db,
      WIH0, WIH1, WHH0, WHH1, WD, B0, B1, BD, FLAG);
  embed_conv<<<Mtok/4, 256, 0, stream>>>(ci, wi, cemb, wemb, cw, cb, EMB, FLAG);
  gemm_bf16<9><<<dim3(Mtok/128, NGP/128), 256, 0, stream>>>(EMB, KP0, WIH0, B0, XG, NGP, NGP, FLAG, 0, 1);
  lstm_c<<<NBLK, 1024, 0, stream>>>(XG, WHH0, H1);
  gemm_bf16<8><<<dim3(Mtok/128, NGP/128), 256, 0, stream>>>(H1, KP1, WIH1, B1, XG, NGP, NGP, FLAG, 0, 1);
  lstm_c<<<NBLK, 1024, 0, stream>>>(XG, WHH1, H2);
  gemm_bf16<8><<<dim3(Mtok/128, 1), 256, 0, stream>>>(H2, KP1, WD, BD, d_out, Tt, Tt, FLAG, 1, 0);
}